// Round 1
// baseline (1722.184 us; speedup 1.0000x reference)
//
#include <hip/hip_runtime.h>
#include <math.h>

#define N_NODES 100000
#define N_EDGES 3200000
#define IN_CH 32
#define HID 64

// ---------------------------------------------------------------------------
// Degree: deg[n] = (# edges with dst==n) + 1 (self loop), dinv = rsqrt(deg)
// ---------------------------------------------------------------------------
__global__ void count_deg_kernel(const int* __restrict__ dst, float* __restrict__ deg) {
    int e = blockIdx.x * blockDim.x + threadIdx.x;
    if (e < N_EDGES) atomicAdd(&deg[dst[e]], 1.0f);
}

__global__ void finalize_deg_kernel(float* __restrict__ deg, float* __restrict__ dinv) {
    int n = blockIdx.x * blockDim.x + threadIdx.x;
    if (n < N_NODES) {
        float d = deg[n] + 1.0f;
        deg[n] = d;
        dinv[n] = rsqrtf(d);
    }
}

// ---------------------------------------------------------------------------
// H = X @ W   (X: [N, K] row-major, W: [K, HID] row-major, H: [N, HID])
// Block = 256 threads = 4 nodes x 64 channels. W staged in LDS.
// ---------------------------------------------------------------------------
template <int K>
__global__ void dense_xw_kernel(const float* __restrict__ X, const float* __restrict__ W,
                                float* __restrict__ H) {
    __shared__ float Wl[K * HID];
    int t = threadIdx.x;
    for (int i = t; i < K * HID; i += 256) Wl[i] = W[i];
    __syncthreads();
    int node = blockIdx.x * 4 + (t >> 6);
    int ch = t & 63;
    if (node >= N_NODES) return;
    const float* xr = X + (long long)node * K;
    float s = 0.0f;
#pragma unroll
    for (int k = 0; k < K; ++k) s += xr[k] * Wl[k * HID + ch];
    H[(long long)node * HID + ch] = s;
}

// ---------------------------------------------------------------------------
// Edge scatter: AGG[dst] += H[src] * dinv[src]*dinv[dst]
// 64 lanes per edge (one channel each). Gather is a coalesced 256B read.
// ---------------------------------------------------------------------------
__global__ void scatter_edges_kernel(const int* __restrict__ src, const int* __restrict__ dst,
                                     const float* __restrict__ dinv,
                                     const float* __restrict__ H, float* __restrict__ AGG) {
    long long gid = (long long)blockIdx.x * blockDim.x + threadIdx.x;
    int e = (int)(gid >> 6);
    int ch = threadIdx.x & 63;
    if (e >= N_EDGES) return;
    int s = src[e];
    int d = dst[e];
    float norm = dinv[s] * dinv[d];
    float v = H[(long long)s * HID + ch] * norm;
    atomicAdd(&AGG[(long long)d * HID + ch], v);
}

// ---------------------------------------------------------------------------
// out = relu(AGG + H*(1/deg) + b)   (written back into AGG)
// ---------------------------------------------------------------------------
__global__ void finalize_layer_kernel(const float* __restrict__ H, const float* __restrict__ deg,
                                      const float* __restrict__ b, float* __restrict__ AGG) {
    int i = blockIdx.x * blockDim.x + threadIdx.x;
    if (i >= N_NODES * HID) return;
    int n = i >> 6;
    int ch = i & 63;
    float v = AGG[i] + H[i] * (1.0f / deg[n]) + b[ch];
    AGG[i] = fmaxf(v, 0.0f);
}

// ---------------------------------------------------------------------------
// out[n] = sigmoid(dot(H[n,:], Wc) + bc)   -- wave-64 reduce, 4 nodes/block
// ---------------------------------------------------------------------------
__global__ void classifier_kernel(const float* __restrict__ H, const float* __restrict__ Wc,
                                  const float* __restrict__ bc, float* __restrict__ out) {
    int t = threadIdx.x;
    int node = blockIdx.x * 4 + (t >> 6);
    int ch = t & 63;
    if (node >= N_NODES) return;
    float v = H[(long long)node * HID + ch] * Wc[ch];
#pragma unroll
    for (int off = 32; off; off >>= 1) v += __shfl_down(v, off, 64);
    if (ch == 0) out[node] = 1.0f / (1.0f + expf(-(v + bc[0])));
}

// ---------------------------------------------------------------------------
extern "C" void kernel_launch(void* const* d_in, const int* in_sizes, int n_in,
                              void* d_out, int out_size, void* d_ws, size_t ws_size,
                              hipStream_t stream) {
    const float* x  = (const float*)d_in[0];
    const int* ei   = (const int*)d_in[1];
    const float* W1 = (const float*)d_in[2];
    const float* b1 = (const float*)d_in[3];
    const float* W2 = (const float*)d_in[4];
    const float* b2 = (const float*)d_in[5];
    const float* Wc = (const float*)d_in[6];
    const float* bc = (const float*)d_in[7];
    float* out = (float*)d_out;

    const int* src = ei;
    const int* dst = ei + N_EDGES;

    // Workspace layout (all float32):
    //   A  : N*HID   (h = X@W, reused per layer)
    //   B  : N*HID   (agg -> layer output, reused)
    //   deg: N
    //   dinv: N
    float* A    = (float*)d_ws;
    float* B    = A + (size_t)N_NODES * HID;
    float* deg  = B + (size_t)N_NODES * HID;
    float* dinv = deg + N_NODES;

    const int B256 = 256;
    int eBlocks    = (N_EDGES + B256 - 1) / B256;
    int nBlocks    = (N_NODES + B256 - 1) / B256;
    int node4      = (N_NODES + 3) / 4;                 // 4 nodes per 256-block
    int nhBlocks   = (N_NODES * HID + B256 - 1) / B256; // elementwise over N*HID
    long long scatterThreads = (long long)N_EDGES * 64;
    int sBlocks    = (int)((scatterThreads + B256 - 1) / B256);

    // ---- degrees (shared by both layers) ----
    hipMemsetAsync(deg, 0, N_NODES * sizeof(float), stream);
    count_deg_kernel<<<eBlocks, B256, 0, stream>>>(dst, deg);
    finalize_deg_kernel<<<nBlocks, B256, 0, stream>>>(deg, dinv);

    // ---- layer 1 ----
    dense_xw_kernel<IN_CH><<<node4, B256, 0, stream>>>(x, W1, A);
    hipMemsetAsync(B, 0, (size_t)N_NODES * HID * sizeof(float), stream);
    scatter_edges_kernel<<<sBlocks, B256, 0, stream>>>(src, dst, dinv, A, B);
    finalize_layer_kernel<<<nhBlocks, B256, 0, stream>>>(A, deg, b1, B);
    // B now holds relu(layer1 out)

    // ---- layer 2 ----
    dense_xw_kernel<HID><<<node4, B256, 0, stream>>>(B, W2, A);
    hipMemsetAsync(B, 0, (size_t)N_NODES * HID * sizeof(float), stream);
    scatter_edges_kernel<<<sBlocks, B256, 0, stream>>>(src, dst, dinv, A, B);
    finalize_layer_kernel<<<nhBlocks, B256, 0, stream>>>(A, deg, b2, B);
    // B now holds relu(layer2 out)

    // ---- classifier ----
    classifier_kernel<<<node4, B256, 0, stream>>>(B, Wc, bc, out);
}

// Round 2
// 784.210 us; speedup vs baseline: 2.1961x; 2.1961x over previous
//
#include <hip/hip_runtime.h>
#include <math.h>

#define N_NODES 100000
#define N_EDGES 3200000
#define IN_CH 32
#define HID 64
#define SCAN_NB ((N_NODES + 1023) / 1024)   // 98 blocks, 1024 elems each

// ---------------------------------------------------------------------------
// Degree count (dst side): degi[n] = # incoming edges
// ---------------------------------------------------------------------------
__global__ void count_deg_kernel(const int* __restrict__ dst, int* __restrict__ degi) {
    int e = blockIdx.x * blockDim.x + threadIdx.x;
    if (e < N_EDGES) atomicAdd(&degi[dst[e]], 1);
}

__global__ void compute_dinv_kernel(const int* __restrict__ degi, float* __restrict__ dinv) {
    int n = blockIdx.x * blockDim.x + threadIdx.x;
    if (n < N_NODES) dinv[n] = rsqrtf((float)degi[n] + 1.0f);
}

// ---------------------------------------------------------------------------
// 3-phase exclusive prefix scan of degi -> rowptr  (N = 100k, 98 x 1024 chunks)
// ---------------------------------------------------------------------------
__global__ void scan_block_totals(const int* __restrict__ degi, int* __restrict__ bsum) {
    __shared__ int lds[256];
    int b = blockIdx.x, t = threadIdx.x;
    int base = b * 1024 + t * 4;
    int s = 0;
#pragma unroll
    for (int j = 0; j < 4; ++j) if (base + j < N_NODES) s += degi[base + j];
    lds[t] = s;
    __syncthreads();
    for (int off = 128; off > 0; off >>= 1) {
        if (t < off) lds[t] += lds[t + off];
        __syncthreads();
    }
    if (t == 0) bsum[b] = lds[0];
}

__global__ void scan_bsums(int* __restrict__ bsum) {
    __shared__ int lds[256];
    int t = threadIdx.x;
    int v = (t < SCAN_NB) ? bsum[t] : 0;
    lds[t] = v;
    __syncthreads();
    for (int off = 1; off < 256; off <<= 1) {
        int x = (t >= off) ? lds[t - off] : 0;
        __syncthreads();
        lds[t] += x;
        __syncthreads();
    }
    if (t < SCAN_NB) bsum[t] = lds[t] - v;   // exclusive
}

__global__ void write_rowptr(const int* __restrict__ degi, const int* __restrict__ bsum,
                             int* __restrict__ rowptr) {
    __shared__ int lds[256];
    int b = blockIdx.x, t = threadIdx.x;
    int base = b * 1024 + t * 4;
    int local[4];
    int s = 0;
#pragma unroll
    for (int j = 0; j < 4; ++j) {
        local[j] = (base + j < N_NODES) ? degi[base + j] : 0;
        s += local[j];
    }
    lds[t] = s;
    __syncthreads();
    for (int off = 1; off < 256; off <<= 1) {
        int x = (t >= off) ? lds[t - off] : 0;
        __syncthreads();
        lds[t] += x;
        __syncthreads();
    }
    int run = bsum[b] + lds[t] - s;   // exclusive prefix for this thread's chunk
#pragma unroll
    for (int j = 0; j < 4; ++j) {
        if (base + j < N_NODES) { rowptr[base + j] = run; run += local[j]; }
    }
    if (b == 0 && t == 0) rowptr[N_NODES] = N_EDGES;
}

// ---------------------------------------------------------------------------
// Placement: bucket edges by dst. esw[pos] = {src, norm} packed 8B.
// fill[] (reused degi, re-zeroed) is the per-node cursor.
// ---------------------------------------------------------------------------
__global__ void place_edges_kernel(const int* __restrict__ src, const int* __restrict__ dst,
                                   const float* __restrict__ dinv, const int* __restrict__ rowptr,
                                   int* __restrict__ fill, int2* __restrict__ esw) {
    int e = blockIdx.x * blockDim.x + threadIdx.x;
    if (e >= N_EDGES) return;
    int s = src[e];
    int d = dst[e];
    int pos = rowptr[d] + atomicAdd(&fill[d], 1);
    int2 p;
    p.x = s;
    p.y = __float_as_int(dinv[s] * dinv[d]);
    esw[pos] = p;
}

// ---------------------------------------------------------------------------
// H = X @ W   (block = 4 nodes x 64 channels, W staged in LDS)
// ---------------------------------------------------------------------------
template <int K>
__global__ void dense_xw_kernel(const float* __restrict__ X, const float* __restrict__ W,
                                float* __restrict__ H) {
    __shared__ float Wl[K * HID];
    int t = threadIdx.x;
    for (int i = t; i < K * HID; i += 256) Wl[i] = W[i];
    __syncthreads();
    int node = blockIdx.x * 4 + (t >> 6);
    int ch = t & 63;
    if (node >= N_NODES) return;
    const float* xr = X + (long long)node * K;
    float s = 0.0f;
#pragma unroll
    for (int k = 0; k < K; ++k) s += xr[k] * Wl[k * HID + ch];
    H[(long long)node * HID + ch] = s;
}

// ---------------------------------------------------------------------------
// Gather-aggregate + fused finalize:
//   Out[n] = relu( sum_{e in CSR[n]} H[src_e]*w_e + H[n]/deg + b )
// One wave (64 lanes = 64 channels) per node; no atomics.
// ---------------------------------------------------------------------------
__global__ void gather_agg_kernel(const int2* __restrict__ esw, const int* __restrict__ rowptr,
                                  const float* __restrict__ H, const float* __restrict__ b,
                                  float* __restrict__ Out) {
    int t = threadIdx.x;
    int node = blockIdx.x * 4 + (t >> 6);
    int ch = t & 63;
    if (node >= N_NODES) return;
    int beg = rowptr[node];
    int end = rowptr[node + 1];
    float acc = 0.0f;
    int i = beg;
    for (; i + 1 < end; i += 2) {
        int2 e0 = esw[i];
        int2 e1 = esw[i + 1];
        float v0 = H[(long long)e0.x * HID + ch] * __int_as_float(e0.y);
        float v1 = H[(long long)e1.x * HID + ch] * __int_as_float(e1.y);
        acc += v0 + v1;
    }
    if (i < end) {
        int2 e0 = esw[i];
        acc += H[(long long)e0.x * HID + ch] * __int_as_float(e0.y);
    }
    float deg = (float)(end - beg) + 1.0f;
    float v = acc + H[(long long)node * HID + ch] * (1.0f / deg) + b[ch];
    Out[(long long)node * HID + ch] = fmaxf(v, 0.0f);
}

// ---------------------------------------------------------------------------
// out[n] = sigmoid(dot(H[n,:], Wc) + bc)
// ---------------------------------------------------------------------------
__global__ void classifier_kernel(const float* __restrict__ H, const float* __restrict__ Wc,
                                  const float* __restrict__ bc, float* __restrict__ out) {
    int t = threadIdx.x;
    int node = blockIdx.x * 4 + (t >> 6);
    int ch = t & 63;
    if (node >= N_NODES) return;
    float v = H[(long long)node * HID + ch] * Wc[ch];
#pragma unroll
    for (int off = 32; off; off >>= 1) v += __shfl_down(v, off, 64);
    if (ch == 0) out[node] = 1.0f / (1.0f + expf(-(v + bc[0])));
}

// ---------------------------------------------------------------------------
extern "C" void kernel_launch(void* const* d_in, const int* in_sizes, int n_in,
                              void* d_out, int out_size, void* d_ws, size_t ws_size,
                              hipStream_t stream) {
    const float* x  = (const float*)d_in[0];
    const int* ei   = (const int*)d_in[1];
    const float* W1 = (const float*)d_in[2];
    const float* b1 = (const float*)d_in[3];
    const float* W2 = (const float*)d_in[4];
    const float* b2 = (const float*)d_in[5];
    const float* Wc = (const float*)d_in[6];
    const float* bc = (const float*)d_in[7];
    float* out = (float*)d_out;

    const int* src = ei;
    const int* dst = ei + N_EDGES;

    // Workspace layout: A[N*HID] f32 | B[N*HID] f32 | esw[E] int2 |
    //                   rowptr[N+1] int | degi[N] int | dinv[N] f32 | bsum[512] int
    float* A     = (float*)d_ws;
    float* B     = A + (size_t)N_NODES * HID;
    int2*  esw   = (int2*)(B + (size_t)N_NODES * HID);
    int*   rowptr = (int*)(esw + N_EDGES);
    int*   degi  = rowptr + (N_NODES + 1);
    float* dinv  = (float*)(degi + N_NODES);
    int*   bsum  = (int*)(dinv + N_NODES);

    const int B256 = 256;
    int eBlocks = (N_EDGES + B256 - 1) / B256;
    int nBlocks = (N_NODES + B256 - 1) / B256;
    int node4   = (N_NODES + 3) / 4;

    // ---- CSR build (shared by both layers) ----
    hipMemsetAsync(degi, 0, N_NODES * sizeof(int), stream);
    count_deg_kernel<<<eBlocks, B256, 0, stream>>>(dst, degi);
    compute_dinv_kernel<<<nBlocks, B256, 0, stream>>>(degi, dinv);
    scan_block_totals<<<SCAN_NB, B256, 0, stream>>>(degi, bsum);
    scan_bsums<<<1, B256, 0, stream>>>(bsum);
    write_rowptr<<<SCAN_NB, B256, 0, stream>>>(degi, bsum, rowptr);
    hipMemsetAsync(degi, 0, N_NODES * sizeof(int), stream);   // reuse as fill cursor
    place_edges_kernel<<<eBlocks, B256, 0, stream>>>(src, dst, dinv, rowptr, degi, esw);

    // ---- layer 1 ----
    dense_xw_kernel<IN_CH><<<node4, B256, 0, stream>>>(x, W1, A);
    gather_agg_kernel<<<node4, B256, 0, stream>>>(esw, rowptr, A, b1, B);

    // ---- layer 2 ----
    dense_xw_kernel<HID><<<node4, B256, 0, stream>>>(B, W2, A);
    gather_agg_kernel<<<node4, B256, 0, stream>>>(esw, rowptr, A, b2, B);

    // ---- classifier ----
    classifier_kernel<<<node4, B256, 0, stream>>>(B, Wc, bc, out);
}

// Round 3
// 639.666 us; speedup vs baseline: 2.6923x; 1.2260x over previous
//
#include <hip/hip_runtime.h>
#include <math.h>

#define N_NODES 100000
#define N_EDGES 3200000
#define IN_CH 32
#define HID 64
#define SCAN_NB ((N_NODES + 1023) / 1024)   // 98 blocks, 1024 elems each

// ---------------------------------------------------------------------------
// Degree count (dst side), int4-vectorized: degi[n] = # incoming edges
// ---------------------------------------------------------------------------
__global__ void count_deg_kernel(const int* __restrict__ dst, int* __restrict__ degi) {
    int i = blockIdx.x * blockDim.x + threadIdx.x;
    if (i >= N_EDGES / 4) return;
    int4 d = ((const int4*)dst)[i];
    atomicAdd(&degi[d.x], 1);
    atomicAdd(&degi[d.y], 1);
    atomicAdd(&degi[d.z], 1);
    atomicAdd(&degi[d.w], 1);
}

__global__ void compute_dinv_kernel(const int* __restrict__ degi, float* __restrict__ dinv) {
    int n = blockIdx.x * blockDim.x + threadIdx.x;
    if (n < N_NODES) dinv[n] = rsqrtf((float)degi[n] + 1.0f);
}

// ---------------------------------------------------------------------------
// 3-phase exclusive prefix scan of degi -> rowptr
// ---------------------------------------------------------------------------
__global__ void scan_block_totals(const int* __restrict__ degi, int* __restrict__ bsum) {
    __shared__ int lds[256];
    int b = blockIdx.x, t = threadIdx.x;
    int base = b * 1024 + t * 4;
    int s = 0;
#pragma unroll
    for (int j = 0; j < 4; ++j) if (base + j < N_NODES) s += degi[base + j];
    lds[t] = s;
    __syncthreads();
    for (int off = 128; off > 0; off >>= 1) {
        if (t < off) lds[t] += lds[t + off];
        __syncthreads();
    }
    if (t == 0) bsum[b] = lds[0];
}

__global__ void scan_bsums(int* __restrict__ bsum) {
    __shared__ int lds[256];
    int t = threadIdx.x;
    int v = (t < SCAN_NB) ? bsum[t] : 0;
    lds[t] = v;
    __syncthreads();
    for (int off = 1; off < 256; off <<= 1) {
        int x = (t >= off) ? lds[t - off] : 0;
        __syncthreads();
        lds[t] += x;
        __syncthreads();
    }
    if (t < SCAN_NB) bsum[t] = lds[t] - v;   // exclusive
}

__global__ void write_rowptr(const int* __restrict__ degi, const int* __restrict__ bsum,
                             int* __restrict__ rowptr) {
    __shared__ int lds[256];
    int b = blockIdx.x, t = threadIdx.x;
    int base = b * 1024 + t * 4;
    int local[4];
    int s = 0;
#pragma unroll
    for (int j = 0; j < 4; ++j) {
        local[j] = (base + j < N_NODES) ? degi[base + j] : 0;
        s += local[j];
    }
    lds[t] = s;
    __syncthreads();
    for (int off = 1; off < 256; off <<= 1) {
        int x = (t >= off) ? lds[t - off] : 0;
        __syncthreads();
        lds[t] += x;
        __syncthreads();
    }
    int run = bsum[b] + lds[t] - s;
#pragma unroll
    for (int j = 0; j < 4; ++j) {
        if (base + j < N_NODES) { rowptr[base + j] = run; run += local[j]; }
    }
    if (b == 0 && t == 0) rowptr[N_NODES] = N_EDGES;
}

// ---------------------------------------------------------------------------
// Placement: esw[pos] = src only (4B). fill[] is the per-node cursor.
// ---------------------------------------------------------------------------
__global__ void place_edges_kernel(const int* __restrict__ src, const int* __restrict__ dst,
                                   const int* __restrict__ rowptr,
                                   int* __restrict__ fill, int* __restrict__ esw) {
    int i = blockIdx.x * blockDim.x + threadIdx.x;
    if (i >= N_EDGES / 4) return;
    int4 s4 = ((const int4*)src)[i];
    int4 d4 = ((const int4*)dst)[i];
    int pos;
    pos = rowptr[d4.x] + atomicAdd(&fill[d4.x], 1);
    __builtin_nontemporal_store(s4.x, &esw[pos]);
    pos = rowptr[d4.y] + atomicAdd(&fill[d4.y], 1);
    __builtin_nontemporal_store(s4.y, &esw[pos]);
    pos = rowptr[d4.z] + atomicAdd(&fill[d4.z], 1);
    __builtin_nontemporal_store(s4.z, &esw[pos]);
    pos = rowptr[d4.w] + atomicAdd(&fill[d4.w], 1);
    __builtin_nontemporal_store(s4.w, &esw[pos]);
}

// ---------------------------------------------------------------------------
// Hs = (X @ W) * dinv[node]   (block = 4 nodes x 64 ch, W + X rows in LDS)
// ---------------------------------------------------------------------------
template <int K>
__global__ void dense_xw_kernel(const float* __restrict__ X, const float* __restrict__ W,
                                const float* __restrict__ dinv, float* __restrict__ Hs) {
    __shared__ float Wl[K * HID];
    __shared__ float Xl[4 * K];
    int t = threadIdx.x;
    int node0 = blockIdx.x * 4;
    for (int i = t; i < K * HID; i += 256) Wl[i] = W[i];
    for (int i = t; i < 4 * K; i += 256) Xl[i] = X[node0 * K + i];
    __syncthreads();
    int w = t >> 6, ch = t & 63;
    int node = node0 + w;
    float s = 0.0f;
#pragma unroll
    for (int k = 0; k < K; ++k) s += Xl[w * K + k] * Wl[k * HID + ch];
    Hs[node * HID + ch] = s * dinv[node];
}

// ---------------------------------------------------------------------------
// Gather-aggregate, 4 edge-groups x 16 lanes x float4 per wave:
//   r = relu( dinv[n]*(sum_e Hs[src_e] + Hs[n]) + b )
// FUSE_CLS: fold the sigmoid classifier in (layer 2), else write r.
// ---------------------------------------------------------------------------
__device__ inline float4 shfl_xor4(float4 v, int mask) {
    float4 r;
    r.x = __shfl_xor(v.x, mask, 64);
    r.y = __shfl_xor(v.y, mask, 64);
    r.z = __shfl_xor(v.z, mask, 64);
    r.w = __shfl_xor(v.w, mask, 64);
    return r;
}

template <bool FUSE_CLS>
__global__ void gather_agg_kernel(const int* __restrict__ esw, const int* __restrict__ rowptr,
                                  const float* __restrict__ dinv, const float* __restrict__ Hs,
                                  const float* __restrict__ b,
                                  const float* __restrict__ Wc, const float* __restrict__ bc,
                                  float* __restrict__ Out) {
    int t = threadIdx.x;
    int node = blockIdx.x * 4 + (t >> 6);   // N_NODES % 4 == 0, grid exact
    int lane = t & 63;
    int g = lane >> 4, s = lane & 15;
    int beg = rowptr[node], end = rowptr[node + 1];
    int cnt = end - beg;
    const float4* H4 = (const float4*)Hs;
    float4 acc = make_float4(0.f, 0.f, 0.f, 0.f);
    int i = g;
    for (; i + 4 < cnt; i += 8) {
        int s0 = esw[beg + i];
        int s1 = esw[beg + i + 4];
        float4 v0 = H4[(long long)s0 * 16 + s];
        float4 v1 = H4[(long long)s1 * 16 + s];
        acc.x += v0.x + v1.x;
        acc.y += v0.y + v1.y;
        acc.z += v0.z + v1.z;
        acc.w += v0.w + v1.w;
    }
    if (i < cnt) {
        int s0 = esw[beg + i];
        float4 v0 = H4[(long long)s0 * 16 + s];
        acc.x += v0.x; acc.y += v0.y; acc.z += v0.z; acc.w += v0.w;
    }
    // reduce across the 4 edge-groups (lanes s, s+16, s+32, s+48)
    float4 o = shfl_xor4(acc, 16);
    acc.x += o.x; acc.y += o.y; acc.z += o.z; acc.w += o.w;
    o = shfl_xor4(acc, 32);
    acc.x += o.x; acc.y += o.y; acc.z += o.z; acc.w += o.w;

    float4 hsn = H4[(long long)node * 16 + s];
    float di = dinv[node];
    float4 bb = ((const float4*)b)[s];
    float4 r;
    r.x = fmaxf(di * (acc.x + hsn.x) + bb.x, 0.f);
    r.y = fmaxf(di * (acc.y + hsn.y) + bb.y, 0.f);
    r.z = fmaxf(di * (acc.z + hsn.z) + bb.z, 0.f);
    r.w = fmaxf(di * (acc.w + hsn.w) + bb.w, 0.f);

    if (!FUSE_CLS) {
        if (g == 0) ((float4*)Out)[(long long)node * 16 + s] = r;
    } else {
        float4 wc = ((const float4*)Wc)[s];
        float v = r.x * wc.x + r.y * wc.y + r.z * wc.z + r.w * wc.w;
#pragma unroll
        for (int off = 1; off < 16; off <<= 1) v += __shfl_xor(v, off, 64);
        if (lane == 0) Out[node] = 1.0f / (1.0f + expf(-(v + bc[0])));
    }
}

// ---------------------------------------------------------------------------
extern "C" void kernel_launch(void* const* d_in, const int* in_sizes, int n_in,
                              void* d_out, int out_size, void* d_ws, size_t ws_size,
                              hipStream_t stream) {
    const float* x  = (const float*)d_in[0];
    const int* ei   = (const int*)d_in[1];
    const float* W1 = (const float*)d_in[2];
    const float* b1 = (const float*)d_in[3];
    const float* W2 = (const float*)d_in[4];
    const float* b2 = (const float*)d_in[5];
    const float* Wc = (const float*)d_in[6];
    const float* bc = (const float*)d_in[7];
    float* out = (float*)d_out;

    const int* src = ei;
    const int* dst = ei + N_EDGES;

    // Workspace: A[N*HID] | B[N*HID] | esw[E] int | rowptr[N+1] | degi[N] | dinv[N] | bsum
    float* A      = (float*)d_ws;
    float* B      = A + (size_t)N_NODES * HID;
    int*   esw    = (int*)(B + (size_t)N_NODES * HID);
    int*   rowptr = esw + N_EDGES;
    int*   degi   = rowptr + (N_NODES + 1);
    float* dinv   = (float*)(degi + N_NODES);
    int*   bsum   = (int*)(dinv + N_NODES);

    const int B256 = 256;
    int e4Blocks = (N_EDGES / 4 + B256 - 1) / B256;   // 3125 exact
    int nBlocks  = (N_NODES + B256 - 1) / B256;
    int node4    = N_NODES / 4;                        // 25000 exact

    // ---- CSR build (shared by both layers) ----
    hipMemsetAsync(degi, 0, N_NODES * sizeof(int), stream);
    count_deg_kernel<<<e4Blocks, B256, 0, stream>>>(dst, degi);
    compute_dinv_kernel<<<nBlocks, B256, 0, stream>>>(degi, dinv);
    scan_block_totals<<<SCAN_NB, B256, 0, stream>>>(degi, bsum);
    scan_bsums<<<1, B256, 0, stream>>>(bsum);
    write_rowptr<<<SCAN_NB, B256, 0, stream>>>(degi, bsum, rowptr);
    hipMemsetAsync(degi, 0, N_NODES * sizeof(int), stream);   // reuse as fill cursor
    place_edges_kernel<<<e4Blocks, B256, 0, stream>>>(src, dst, rowptr, degi, esw);

    // ---- layer 1 ----
    dense_xw_kernel<IN_CH><<<node4, B256, 0, stream>>>(x, W1, dinv, A);
    gather_agg_kernel<false><<<node4, B256, 0, stream>>>(esw, rowptr, dinv, A, b1,
                                                         nullptr, nullptr, B);

    // ---- layer 2 + fused classifier ----
    dense_xw_kernel<HID><<<node4, B256, 0, stream>>>(B, W2, dinv, A);
    gather_agg_kernel<true><<<node4, B256, 0, stream>>>(esw, rowptr, dinv, A, b2,
                                                        Wc, bc, out);
}

// Round 4
// 307.549 us; speedup vs baseline: 5.5997x; 2.0799x over previous
//
#include <hip/hip_runtime.h>
#include <math.h>

#define N_NODES 100000
#define N_EDGES 3200000
#define IN_CH 32
#define HID 64
#define BW 512                              // dst nodes per bucket
#define NB ((N_NODES + BW - 1) / BW)        // 196 buckets
#define K3_CHUNK 8192                       // edges per partition block
#define K3_BLOCKS ((N_EDGES + K3_CHUNK - 1) / K3_CHUNK)   // 391

typedef unsigned short ushort_t;

// ---------------- bf16 helpers ----------------
__device__ __forceinline__ float bflo(unsigned u) { return __uint_as_float(u << 16); }
__device__ __forceinline__ float bfhi(unsigned u) { return __uint_as_float(u & 0xffff0000u); }
__device__ __forceinline__ unsigned packbf(float a, float b) {
    unsigned ua = __float_as_uint(a); ua += 0x7fffu + ((ua >> 16) & 1u);
    unsigned ub = __float_as_uint(b); ub += 0x7fffu + ((ub >> 16) & 1u);
    return (ua >> 16) | (ub & 0xffff0000u);
}
__device__ __forceinline__ ushort_t f2bf(float a) {
    unsigned ua = __float_as_uint(a); ua += 0x7fffu + ((ua >> 16) & 1u);
    return (ushort_t)(ua >> 16);
}
__device__ __forceinline__ float bf2f(ushort_t u) { return __uint_as_float(((unsigned)u) << 16); }

// ---------------------------------------------------------------------------
// K1: bucket histogram over dst>>9 (LDS-staged, few global atomics)
// ---------------------------------------------------------------------------
__global__ void bucket_hist_kernel(const int* __restrict__ dst, int* __restrict__ bhist) {
    __shared__ int h[NB];
    int t = threadIdx.x;
    for (int i = t; i < NB; i += 256) h[i] = 0;
    __syncthreads();
    const int4* d4 = (const int4*)dst;
    int i0 = blockIdx.x * (K3_CHUNK / 4) + t;
#pragma unroll
    for (int j = 0; j < K3_CHUNK / 1024; ++j) {
        int i4 = i0 + j * 256;
        if (i4 < N_EDGES / 4) {
            int4 d = d4[i4];
            atomicAdd(&h[d.x >> 9], 1);
            atomicAdd(&h[d.y >> 9], 1);
            atomicAdd(&h[d.z >> 9], 1);
            atomicAdd(&h[d.w >> 9], 1);
        }
    }
    __syncthreads();
    for (int i = t; i < NB; i += 256)
        if (h[i]) atomicAdd(&bhist[i], h[i]);
}

// ---------------------------------------------------------------------------
// K2: exclusive scan of the 196 bucket totals (one block)
// ---------------------------------------------------------------------------
__global__ void scan_buckets_kernel(const int* __restrict__ bhist, int* __restrict__ gbase,
                                    int* __restrict__ gcursor, int* __restrict__ rowptr) {
    __shared__ int sa[256], sb[256];
    int t = threadIdx.x;
    int v = (t < NB) ? bhist[t] : 0;
    sa[t] = v;
    __syncthreads();
    int* pa = sa; int* pb = sb;
    for (int off = 1; off < 256; off <<= 1) {
        int add = (t >= off) ? pa[t - off] : 0;
        pb[t] = pa[t] + add;
        __syncthreads();
        int* tmp = pa; pa = pb; pb = tmp;
    }
    int excl = pa[t] - v;
    if (t <= NB) { gbase[t] = (t == NB) ? N_EDGES : excl; }
    if (t < NB) gcursor[t] = excl;
    if (t == 0) rowptr[N_NODES] = N_EDGES;
}

// ---------------------------------------------------------------------------
// K3: partition edges into bucket-contiguous (src,dst) runs
// ---------------------------------------------------------------------------
__global__ void partition_kernel(const int* __restrict__ src, const int* __restrict__ dst,
                                 int* __restrict__ gcursor, int2* __restrict__ gsw) {
    __shared__ int h[NB], lbase[NB], lcur[NB];
    int t = threadIdx.x;
    for (int i = t; i < NB; i += 256) { h[i] = 0; lcur[i] = 0; }
    __syncthreads();
    const int4* d4 = (const int4*)dst;
    const int4* s4 = (const int4*)src;
    int i0 = blockIdx.x * (K3_CHUNK / 4) + t;
#pragma unroll
    for (int j = 0; j < K3_CHUNK / 1024; ++j) {
        int i4 = i0 + j * 256;
        if (i4 < N_EDGES / 4) {
            int4 d = d4[i4];
            atomicAdd(&h[d.x >> 9], 1);
            atomicAdd(&h[d.y >> 9], 1);
            atomicAdd(&h[d.z >> 9], 1);
            atomicAdd(&h[d.w >> 9], 1);
        }
    }
    __syncthreads();
    for (int i = t; i < NB; i += 256)
        lbase[i] = h[i] ? atomicAdd(&gcursor[i], h[i]) : 0;
    __syncthreads();
#pragma unroll
    for (int j = 0; j < K3_CHUNK / 1024; ++j) {
        int i4 = i0 + j * 256;
        if (i4 < N_EDGES / 4) {
            int4 d = d4[i4];
            int4 s = s4[i4];
            int b, r;
            b = d.x >> 9; r = atomicAdd(&lcur[b], 1); gsw[lbase[b] + r] = make_int2(s.x, d.x);
            b = d.y >> 9; r = atomicAdd(&lcur[b], 1); gsw[lbase[b] + r] = make_int2(s.y, d.y);
            b = d.z >> 9; r = atomicAdd(&lcur[b], 1); gsw[lbase[b] + r] = make_int2(s.z, d.z);
            b = d.w >> 9; r = atomicAdd(&lcur[b], 1); gsw[lbase[b] + r] = make_int2(s.w, d.w);
        }
    }
}

// ---------------------------------------------------------------------------
// K4: per-bucket exact CSR placement. One block (512 thr) per bucket.
// Produces rowptr, dinv, esw. All per-dst counters/cursors live in LDS.
// ---------------------------------------------------------------------------
__global__ __launch_bounds__(512) void bucket_place_kernel(
        const int2* __restrict__ gsw, const int* __restrict__ gbase,
        int* __restrict__ rowptr, float* __restrict__ dinv, int* __restrict__ esw) {
    __shared__ int cnt[BW], exc[BW], cur[BW];
    __shared__ int sa[BW], sb[BW];
    int t = threadIdx.x;           // 0..511
    int k = blockIdx.x;            // bucket id
    int d0 = k * BW;
    cnt[t] = 0; cur[t] = 0;
    __syncthreads();
    int beg = gbase[k], end = gbase[k + 1];
    for (int i = beg + t; i < end; i += 512)
        atomicAdd(&cnt[gsw[i].y - d0], 1);
    __syncthreads();
    // exclusive scan of cnt[512]
    sa[t] = cnt[t];
    __syncthreads();
    int* pa = sa; int* pb = sb;
    for (int off = 1; off < 512; off <<= 1) {
        int add = (t >= off) ? pa[t - off] : 0;
        pb[t] = pa[t] + add;
        __syncthreads();
        int* tmp = pa; pa = pb; pb = tmp;
    }
    int e_x = pa[t] - cnt[t];
    exc[t] = e_x;
    int d = d0 + t;
    if (d < N_NODES) {
        rowptr[d] = beg + e_x;
        dinv[d] = rsqrtf((float)cnt[t] + 1.0f);
    }
    __syncthreads();
    for (int i = beg + t; i < end; i += 512) {
        int2 e = gsw[i];
        int ld = e.y - d0;
        int r = atomicAdd(&cur[ld], 1);
        esw[beg + exc[ld] + r] = e.x;
    }
}

// ---------------------------------------------------------------------------
// Hs = (X @ W) * dinv[node], output bf16. 16 nodes per block, 4 per thread.
// ---------------------------------------------------------------------------
template <int K, bool BF16IN>
__global__ void dense_xw_kernel(const void* __restrict__ Xv, const float* __restrict__ W,
                                const float* __restrict__ dinv, ushort_t* __restrict__ Hs) {
    __shared__ float Wl[K * HID];
    __shared__ float Xl[16 * K];
    int t = threadIdx.x;
    int node0 = blockIdx.x * 16;
    for (int i = t; i < K * HID; i += 256) Wl[i] = W[i];
    if (BF16IN) {
        const ushort_t* X = (const ushort_t*)Xv;
        for (int i = t; i < 16 * K; i += 256) Xl[i] = bf2f(X[node0 * K + i]);
    } else {
        const float* X = (const float*)Xv;
        for (int i = t; i < 16 * K; i += 256) Xl[i] = X[node0 * K + i];
    }
    __syncthreads();
    int ch = t & 63;
    int nq = t >> 6;               // 0..3, handles nodes nq*4 .. nq*4+3
    float s0 = 0.f, s1 = 0.f, s2 = 0.f, s3 = 0.f;
#pragma unroll
    for (int k = 0; k < K; ++k) {
        float w = Wl[k * HID + ch];
        s0 += Xl[(nq * 4 + 0) * K + k] * w;
        s1 += Xl[(nq * 4 + 1) * K + k] * w;
        s2 += Xl[(nq * 4 + 2) * K + k] * w;
        s3 += Xl[(nq * 4 + 3) * K + k] * w;
    }
    int n = node0 + nq * 4;
    Hs[(n + 0) * HID + ch] = f2bf(s0 * dinv[n + 0]);
    Hs[(n + 1) * HID + ch] = f2bf(s1 * dinv[n + 1]);
    Hs[(n + 2) * HID + ch] = f2bf(s2 * dinv[n + 2]);
    Hs[(n + 3) * HID + ch] = f2bf(s3 * dinv[n + 3]);
}

// ---------------------------------------------------------------------------
// Gather-aggregate over bf16 Hs. 4 edge-groups x 16 lanes x 8B per wave.
//   r = relu( dinv[n]*(sum_e Hs[src_e] + Hs[n]) + b )
// FUSE_CLS: fold sigmoid classifier (layer 2), else write bf16 r.
// ---------------------------------------------------------------------------
template <bool FUSE_CLS>
__global__ void gather_agg_kernel(const int* __restrict__ esw, const int* __restrict__ rowptr,
                                  const float* __restrict__ dinv, const ushort_t* __restrict__ Hs,
                                  const float* __restrict__ b,
                                  const float* __restrict__ Wc, const float* __restrict__ bc,
                                  void* __restrict__ Outv) {
    int t = threadIdx.x;
    int node = blockIdx.x * 4 + (t >> 6);   // N_NODES % 4 == 0
    int lane = t & 63;
    int g = lane >> 4, s = lane & 15;
    int beg = rowptr[node], end = rowptr[node + 1];
    int cnt = end - beg;
    const uint2* H8 = (const uint2*)Hs;     // 8B = 4 bf16 channels
    float4 acc = make_float4(0.f, 0.f, 0.f, 0.f);
    int i = g;
    for (; i + 12 < cnt; i += 16) {
        int s0 = esw[beg + i];
        int s1 = esw[beg + i + 4];
        int s2 = esw[beg + i + 8];
        int s3 = esw[beg + i + 12];
        uint2 v0 = H8[s0 * 16 + s];
        uint2 v1 = H8[s1 * 16 + s];
        uint2 v2 = H8[s2 * 16 + s];
        uint2 v3 = H8[s3 * 16 + s];
        acc.x += (bflo(v0.x) + bflo(v1.x)) + (bflo(v2.x) + bflo(v3.x));
        acc.y += (bfhi(v0.x) + bfhi(v1.x)) + (bfhi(v2.x) + bfhi(v3.x));
        acc.z += (bflo(v0.y) + bflo(v1.y)) + (bflo(v2.y) + bflo(v3.y));
        acc.w += (bfhi(v0.y) + bfhi(v1.y)) + (bfhi(v2.y) + bfhi(v3.y));
    }
    for (; i < cnt; i += 4) {
        int s0 = esw[beg + i];
        uint2 v0 = H8[s0 * 16 + s];
        acc.x += bflo(v0.x);
        acc.y += bfhi(v0.x);
        acc.z += bflo(v0.y);
        acc.w += bfhi(v0.y);
    }
    // reduce across the 4 edge-groups
    acc.x += __shfl_xor(acc.x, 16, 64); acc.y += __shfl_xor(acc.y, 16, 64);
    acc.z += __shfl_xor(acc.z, 16, 64); acc.w += __shfl_xor(acc.w, 16, 64);
    acc.x += __shfl_xor(acc.x, 32, 64); acc.y += __shfl_xor(acc.y, 32, 64);
    acc.z += __shfl_xor(acc.z, 32, 64); acc.w += __shfl_xor(acc.w, 32, 64);

    uint2 hn = H8[node * 16 + s];
    float di = dinv[node];
    float4 bb = ((const float4*)b)[s];
    float4 r;
    r.x = fmaxf(di * (acc.x + bflo(hn.x)) + bb.x, 0.f);
    r.y = fmaxf(di * (acc.y + bfhi(hn.x)) + bb.y, 0.f);
    r.z = fmaxf(di * (acc.z + bflo(hn.y)) + bb.z, 0.f);
    r.w = fmaxf(di * (acc.w + bfhi(hn.y)) + bb.w, 0.f);

    if (!FUSE_CLS) {
        if (g == 0) {
            uint2 o;
            o.x = packbf(r.x, r.y);
            o.y = packbf(r.z, r.w);
            ((uint2*)Outv)[node * 16 + s] = o;
        }
    } else {
        float4 wc = ((const float4*)Wc)[s];
        float v = r.x * wc.x + r.y * wc.y + r.z * wc.z + r.w * wc.w;
#pragma unroll
        for (int off = 1; off < 16; off <<= 1) v += __shfl_xor(v, off, 64);
        if (lane == 0) ((float*)Outv)[node] = 1.0f / (1.0f + expf(-(v + bc[0])));
    }
}

// ---------------------------------------------------------------------------
extern "C" void kernel_launch(void* const* d_in, const int* in_sizes, int n_in,
                              void* d_out, int out_size, void* d_ws, size_t ws_size,
                              hipStream_t stream) {
    const float* x  = (const float*)d_in[0];
    const int* ei   = (const int*)d_in[1];
    const float* W1 = (const float*)d_in[2];
    const float* b1 = (const float*)d_in[3];
    const float* W2 = (const float*)d_in[4];
    const float* b2 = (const float*)d_in[5];
    const float* Wc = (const float*)d_in[6];
    const float* bc = (const float*)d_in[7];
    float* out = (float*)d_out;

    const int* src = ei;
    const int* dst = ei + N_EDGES;

    // Workspace layout (aligned, ~65 MB):
    int2*  gsw    = (int2*)d_ws;                         // E * 8B
    int*   esw    = (int*)(gsw + N_EDGES);               // E * 4B
    int*   rowptr = esw + N_EDGES;                       // N+8
    float* dinv   = (float*)(rowptr + N_NODES + 8);      // N
    int*   bhist  = (int*)(dinv + N_NODES);              // 256
    int*   gbase  = bhist + 256;                         // 256 (NB+1 used)
    int*   gcursor= gbase + 256;                         // 256
    ushort_t* A   = (ushort_t*)(gcursor + 256);          // N*HID bf16
    ushort_t* B   = A + (size_t)N_NODES * HID;           // N*HID bf16

    int node16 = N_NODES / 16;   // 6250, exact
    int node4  = N_NODES / 4;    // 25000, exact

    // ---- CSR build (bucket sort, no global per-dst atomics) ----
    hipMemsetAsync(bhist, 0, 256 * sizeof(int), stream);
    bucket_hist_kernel<<<K3_BLOCKS, 256, 0, stream>>>(dst, bhist);
    scan_buckets_kernel<<<1, 256, 0, stream>>>(bhist, gbase, gcursor, rowptr);
    partition_kernel<<<K3_BLOCKS, 256, 0, stream>>>(src, dst, gcursor, gsw);
    bucket_place_kernel<<<NB, 512, 0, stream>>>(gsw, gbase, rowptr, dinv, esw);

    // ---- layer 1 ----
    dense_xw_kernel<IN_CH, false><<<node16, 256, 0, stream>>>(x, W1, dinv, A);
    gather_agg_kernel<false><<<node4, 256, 0, stream>>>(esw, rowptr, dinv, A, b1,
                                                        nullptr, nullptr, B);

    // ---- layer 2 + fused classifier ----
    dense_xw_kernel<HID, true><<<node16, 256, 0, stream>>>(B, W2, dinv, A);
    gather_agg_kernel<true><<<node4, 256, 0, stream>>>(esw, rowptr, dinv, A, b2,
                                                       Wc, bc, out);
}